// Round 3
// baseline (417.115 us; speedup 1.0000x reference)
//
#include <hip/hip_runtime.h>
#include <math.h>

#define N_NODES 50000
#define F_IN 128
#define NE 800000
#define NH1 8
#define ND1 16
#define ND2 8
#define NEG 0.2f

__device__ __forceinline__ float lrelu(float v) { return v > 0.f ? v : NEG * v; }
__device__ __forceinline__ float elu1(float v)  { return v > 0.f ? v : (__expf(v) - 1.f); }

__device__ __forceinline__ unsigned short f2bf(float f) {
    union { float f; unsigned int i; } c; c.f = f;
    unsigned int u = c.i;
    return (unsigned short)((u + 0x7FFFu + ((u >> 16) & 1u)) >> 16);
}
__device__ __forceinline__ float bflo(unsigned int u) {
    union { unsigned int i; float f; } c; c.i = u << 16; return c.f;
}
__device__ __forceinline__ float bfhi(unsigned int u) {
    union { unsigned int i; float f; } c; c.i = u & 0xFFFF0000u; return c.f;
}

// ---------------- edge dtype detection (int32 vs int64) ----------------
__global__ void detect_kernel(const int* __restrict__ ei, int* __restrict__ flag) {
    if (blockIdx.x == 0 && threadIdx.x == 0) {
        int all0 = 1;
        for (int k = 0; k < 64; ++k) {
            if (ei[2 * k + 1] != 0) { all0 = 0; break; }
        }
        *flag = all0;   // 1 => data is int64 (high words zero), 0 => int32
    }
}

// ---------------- CSR build ----------------
__global__ void init_counts_kernel(int* __restrict__ counts) {
    int i = blockIdx.x * blockDim.x + threadIdx.x;
    if (i < N_NODES) counts[i] = 1;   // self-loop
}

__global__ void hist_kernel(const int* __restrict__ ei, const int* __restrict__ flag,
                            int* __restrict__ counts) {
    int e = blockIdx.x * blockDim.x + threadIdx.x;
    if (e >= NE) return;
    int is64 = *flag;
    int d = is64 ? ei[2 * NE + 2 * e] : ei[NE + e];
    atomicAdd(&counts[d], 1);
}

__global__ __launch_bounds__(1024) void scan_kernel(const int* __restrict__ counts,
                                                    int* __restrict__ rowptr,
                                                    int* __restrict__ cursor) {
    __shared__ int wsum[16];
    __shared__ int wpre[16];
    __shared__ int s_total;
    const int t = threadIdx.x;
    const int lane = t & 63, w = t >> 6;
    int carry = 0;
    if (t == 0) rowptr[0] = 0;
    for (int base = 0; base < N_NODES; base += 1024) {
        int i = base + t;
        int orig = (i < N_NODES) ? counts[i] : 0;
        int v = orig;
        #pragma unroll
        for (int off = 1; off < 64; off <<= 1) {
            int u = __shfl_up(v, off, 64);
            if (lane >= off) v += u;
        }
        if (lane == 63) wsum[w] = v;
        __syncthreads();
        if (t == 0) {
            int s = 0;
            #pragma unroll
            for (int j = 0; j < 16; ++j) { wpre[j] = s; s += wsum[j]; }
            s_total = s;
        }
        __syncthreads();
        int incl = v + wpre[w] + carry;
        if (i < N_NODES) { rowptr[i + 1] = incl; cursor[i] = incl - orig; }
        carry += s_total;
        __syncthreads();
    }
}

__global__ void fill_kernel(const int* __restrict__ ei, const int* __restrict__ flag,
                            int* __restrict__ cursor, int* __restrict__ esrc) {
    int i = blockIdx.x * blockDim.x + threadIdx.x;
    if (i >= NE + N_NODES) return;
    int is64 = *flag;
    int s, d;
    if (i < NE) {
        if (is64) { s = ei[2 * i]; d = ei[2 * NE + 2 * i]; }
        else      { s = ei[i];     d = ei[NE + i]; }
    } else {
        s = d = i - NE;
    }
    int slot = atomicAdd(&cursor[d], 1);
    esrc[slot] = s;
}

// ---------------- conv1 GEMM: h1 = x @ W1, fused attention scores, bf16 output ----------------
__global__ __launch_bounds__(256) void gemm1_kernel(const float* __restrict__ x,
                                                    const float* __restrict__ W,
                                                    const float* __restrict__ att_src,
                                                    const float* __restrict__ att_dst,
                                                    unsigned int* __restrict__ h1b,
                                                    float* __restrict__ a_src1,
                                                    float* __restrict__ a_dst1) {
    __shared__ float Ws[32 * 128];
    __shared__ float Xs[32 * 68];   // transposed x chunk, stride 68 (16B-aligned rows)
    const int t = threadIdx.x;
    const int cg = t & 31;          // col group -> cols cg*4..+3
    const int rg = t >> 5;          // row group -> rows rg*8..+7
    const int row0 = blockIdx.x * 64;

    float acc[8][4];
    #pragma unroll
    for (int i = 0; i < 8; ++i)
        #pragma unroll
        for (int j = 0; j < 4; ++j) acc[i][j] = 0.f;

    for (int kc = 0; kc < 4; ++kc) {
        // stage W chunk (32 x 128)
        #pragma unroll
        for (int i = 0; i < 4; ++i) {
            int fidx = i * 256 + t;
            const float4 wv = *reinterpret_cast<const float4*>(W + kc * 32 * 128 + fidx * 4);
            *reinterpret_cast<float4*>(&Ws[fidx * 4]) = wv;
        }
        // stage x chunk transposed: Xs[kk][r] = x[row0+r][kc*32+kk]
        {
            int r = t >> 2;
            int k4a = t & 3;
            int grow = row0 + r;
            #pragma unroll
            for (int p = 0; p < 2; ++p) {
                int k4 = k4a + p * 4;
                float4 xv = make_float4(0.f, 0.f, 0.f, 0.f);
                if (grow < N_NODES)
                    xv = *reinterpret_cast<const float4*>(x + grow * F_IN + kc * 32 + k4 * 4);
                Xs[(k4 * 4 + 0) * 68 + r] = xv.x;
                Xs[(k4 * 4 + 1) * 68 + r] = xv.y;
                Xs[(k4 * 4 + 2) * 68 + r] = xv.z;
                Xs[(k4 * 4 + 3) * 68 + r] = xv.w;
            }
        }
        __syncthreads();
        #pragma unroll
        for (int kk = 0; kk < 32; ++kk) {
            float4 wv = *reinterpret_cast<const float4*>(&Ws[kk * 128 + cg * 4]);
            float4 xa = *reinterpret_cast<const float4*>(&Xs[kk * 68 + rg * 8]);
            float4 xb = *reinterpret_cast<const float4*>(&Xs[kk * 68 + rg * 8 + 4]);
            float xr[8] = {xa.x, xa.y, xa.z, xa.w, xb.x, xb.y, xb.z, xb.w};
            float wr[4] = {wv.x, wv.y, wv.z, wv.w};
            #pragma unroll
            for (int i = 0; i < 8; ++i)
                #pragma unroll
                for (int j = 0; j < 4; ++j)
                    acc[i][j] = fmaf(xr[i], wr[j], acc[i][j]);
        }
        __syncthreads();
    }
    // epilogue: bf16 store + fused attention score partials
    const int h = cg >> 2;          // head 0..7
    const int q = cg & 3;           // quarter within head (dims 4q..4q+3)
    float as0 = att_src[h * ND1 + 4 * q + 0], as1 = att_src[h * ND1 + 4 * q + 1];
    float as2 = att_src[h * ND1 + 4 * q + 2], as3 = att_src[h * ND1 + 4 * q + 3];
    float ad0 = att_dst[h * ND1 + 4 * q + 0], ad1 = att_dst[h * ND1 + 4 * q + 1];
    float ad2 = att_dst[h * ND1 + 4 * q + 2], ad3 = att_dst[h * ND1 + 4 * q + 3];
    #pragma unroll
    for (int i = 0; i < 8; ++i) {
        int grow = row0 + rg * 8 + i;
        float ps = acc[i][0] * as0 + acc[i][1] * as1 + acc[i][2] * as2 + acc[i][3] * as3;
        float pd = acc[i][0] * ad0 + acc[i][1] * ad1 + acc[i][2] * ad2 + acc[i][3] * ad3;
        ps += __shfl_xor(ps, 1, 64); ps += __shfl_xor(ps, 2, 64);
        pd += __shfl_xor(pd, 1, 64); pd += __shfl_xor(pd, 2, 64);
        if (grow < N_NODES) {
            uint2 wv;
            wv.x = (unsigned int)f2bf(acc[i][0]) | ((unsigned int)f2bf(acc[i][1]) << 16);
            wv.y = (unsigned int)f2bf(acc[i][2]) | ((unsigned int)f2bf(acc[i][3]) << 16);
            *reinterpret_cast<uint2*>(h1b + (size_t)grow * 64 + cg * 2) = wv;
            if (q == 0) {
                a_src1[grow * 8 + h] = ps;
                a_dst1[grow * 8 + h] = pd;
            }
        }
    }
}

// ---------------- conv1 aggregation: one wave per dst node, bf16 gather ----------------
__global__ __launch_bounds__(256) void agg1_kernel(const unsigned int* __restrict__ h1b,
                                                   const float* __restrict__ a_src,
                                                   const float* __restrict__ a_dst,
                                                   const int* __restrict__ rowptr,
                                                   const int* __restrict__ esrc,
                                                   const float* __restrict__ b1,
                                                   float* __restrict__ hout) {
    int wid = (blockIdx.x * 256 + threadIdx.x) >> 6;   // node id (wave-uniform)
    if (wid >= N_NODES) return;
    const int lane = threadIdx.x & 63;
    const int h = lane >> 3;                            // head for this lane's 2 dims
    const float ad = a_dst[wid * 8 + h];
    float acc0 = 0.f, acc1 = 0.f, den = 0.f;
    int j = rowptr[wid];
    const int jend = rowptr[wid + 1];
    for (; j + 4 <= jend; j += 4) {
        int s0 = esrc[j], s1 = esrc[j + 1], s2 = esrc[j + 2], s3 = esrc[j + 3];
        float e0 = a_src[s0 * 8 + h], e1 = a_src[s1 * 8 + h];
        float e2 = a_src[s2 * 8 + h], e3 = a_src[s3 * 8 + h];
        unsigned int u0 = h1b[(size_t)s0 * 64 + lane];
        unsigned int u1 = h1b[(size_t)s1 * 64 + lane];
        unsigned int u2 = h1b[(size_t)s2 * 64 + lane];
        unsigned int u3 = h1b[(size_t)s3 * 64 + lane];
        float p0 = __expf(lrelu(e0 + ad));
        float p1 = __expf(lrelu(e1 + ad));
        float p2 = __expf(lrelu(e2 + ad));
        float p3 = __expf(lrelu(e3 + ad));
        den += (p0 + p1) + (p2 + p3);
        acc0 = fmaf(p0, bflo(u0), acc0); acc1 = fmaf(p0, bfhi(u0), acc1);
        acc0 = fmaf(p1, bflo(u1), acc0); acc1 = fmaf(p1, bfhi(u1), acc1);
        acc0 = fmaf(p2, bflo(u2), acc0); acc1 = fmaf(p2, bfhi(u2), acc1);
        acc0 = fmaf(p3, bflo(u3), acc0); acc1 = fmaf(p3, bfhi(u3), acc1);
    }
    for (; j < jend; ++j) {
        int s = esrc[j];
        float e = a_src[s * 8 + h];
        unsigned int u = h1b[(size_t)s * 64 + lane];
        float p = __expf(lrelu(e + ad));
        den += p;
        acc0 = fmaf(p, bflo(u), acc0);
        acc1 = fmaf(p, bfhi(u), acc1);
    }
    float inv = 1.f / den;
    float2 bb = *reinterpret_cast<const float2*>(b1 + 2 * lane);
    float o0 = elu1(acc0 * inv + bb.x);
    float o1 = elu1(acc1 * inv + bb.y);
    *reinterpret_cast<float2*>(hout + (size_t)wid * F_IN + 2 * lane) = make_float2(o0, o1);
}

// ---------------- conv2 GEMM + attention scores ----------------
__global__ __launch_bounds__(256) void gemm2_kernel(const float* __restrict__ h,
                                                    const float* __restrict__ W2,
                                                    const float* __restrict__ att_src2,
                                                    const float* __restrict__ att_dst2,
                                                    float* __restrict__ h2,
                                                    float* __restrict__ a_src2,
                                                    float* __restrict__ a_dst2) {
    __shared__ float Ws[F_IN * ND2];     // 4 KB
    __shared__ float Hs[32 * 132];       // padded, ~16.9 KB
    int t = threadIdx.x;
    int node0 = blockIdx.x * 32;
    #pragma unroll
    for (int i = 0; i < 4; ++i) { int idx = i * 256 + t; Ws[idx] = W2[idx]; }
    #pragma unroll
    for (int i = 0; i < 4; ++i) {
        int fidx = i * 256 + t;
        int r = fidx >> 5;
        int c4 = fidx & 31;
        int grow = node0 + r;
        float4 v = make_float4(0.f, 0.f, 0.f, 0.f);
        if (grow < N_NODES) v = *reinterpret_cast<const float4*>(h + (size_t)grow * F_IN + c4 * 4);
        *reinterpret_cast<float4*>(&Hs[r * 132 + c4 * 4]) = v;
    }
    __syncthreads();
    int nsub = t >> 3, d = t & 7;
    int node = node0 + nsub;
    float acc = 0.f;
    #pragma unroll 8
    for (int k = 0; k < F_IN; ++k)
        acc = fmaf(Hs[nsub * 132 + k], Ws[k * ND2 + d], acc);
    float vs = acc * att_src2[d];
    float vd = acc * att_dst2[d];
    #pragma unroll
    for (int off = 4; off >= 1; off >>= 1) {
        vs += __shfl_xor(vs, off, 8);
        vd += __shfl_xor(vd, off, 8);
    }
    if (node < N_NODES) {
        h2[node * ND2 + d] = acc;
        if (d == 0) { a_src2[node] = vs; a_dst2[node] = vd; }
    }
}

// ---------------- conv2 aggregation: one thread per node ----------------
__global__ void agg2_kernel(const float* __restrict__ h2,
                            const float* __restrict__ a_src2, const float* __restrict__ a_dst2,
                            const int* __restrict__ rowptr, const int* __restrict__ esrc,
                            const float* __restrict__ b2, float* __restrict__ g) {
    int n = blockIdx.x * blockDim.x + threadIdx.x;
    if (n >= N_NODES) return;
    float ad = a_dst2[n];
    float acc[8] = {0.f, 0.f, 0.f, 0.f, 0.f, 0.f, 0.f, 0.f};
    float den = 0.f;
    int jend = rowptr[n + 1];
    for (int j = rowptr[n]; j < jend; ++j) {
        int s = esrc[j];
        float p = __expf(lrelu(a_src2[s] + ad));
        den += p;
        float4 va = *reinterpret_cast<const float4*>(h2 + s * ND2);
        float4 vb = *reinterpret_cast<const float4*>(h2 + s * ND2 + 4);
        acc[0] = fmaf(p, va.x, acc[0]); acc[1] = fmaf(p, va.y, acc[1]);
        acc[2] = fmaf(p, va.z, acc[2]); acc[3] = fmaf(p, va.w, acc[3]);
        acc[4] = fmaf(p, vb.x, acc[4]); acc[5] = fmaf(p, vb.y, acc[5]);
        acc[6] = fmaf(p, vb.z, acc[6]); acc[7] = fmaf(p, vb.w, acc[7]);
    }
    float inv = 1.f / den;
    float4 o0 = make_float4(elu1(acc[0] * inv + b2[0]), elu1(acc[1] * inv + b2[1]),
                            elu1(acc[2] * inv + b2[2]), elu1(acc[3] * inv + b2[3]));
    float4 o1 = make_float4(elu1(acc[4] * inv + b2[4]), elu1(acc[5] * inv + b2[5]),
                            elu1(acc[6] * inv + b2[6]), elu1(acc[7] * inv + b2[7]));
    *reinterpret_cast<float4*>(g + n * ND2)     = o0;
    *reinterpret_cast<float4*>(g + n * ND2 + 4) = o1;
}

// ---------------- fc1 partial: z(400000) . fc1_w(400000x84) ----------------
// Thread layout: c4 = t%21 (float4 column), r = t/21 (12 rows/iter, 252 active).
// Wave lanes read 16*t contiguous bytes -> one 1KB coalesced segment per wave.
__global__ __launch_bounds__(256) void fc1_kernel(const float* __restrict__ z,
                                                  const float* __restrict__ w,
                                                  float* __restrict__ part) {
    __shared__ float4 red[252];
    const int t = threadIdx.x;
    const int c4 = t % 21;
    const int r  = t / 21;
    float4 acc = make_float4(0.f, 0.f, 0.f, 0.f);
    if (t < 252) {
        const int Z = N_NODES * ND2;                 // 400000
        const int stride = gridDim.x * 12;
        #pragma unroll 2
        for (int i = blockIdx.x * 12 + r; i < Z; i += stride) {
            float zv = z[i];
            float4 wv = *reinterpret_cast<const float4*>(w + (size_t)i * 84 + c4 * 4);
            acc.x = fmaf(zv, wv.x, acc.x);
            acc.y = fmaf(zv, wv.y, acc.y);
            acc.z = fmaf(zv, wv.z, acc.z);
            acc.w = fmaf(zv, wv.w, acc.w);
        }
        red[t] = acc;
    }
    __syncthreads();
    if (t < 21) {
        float4 s = red[t];
        #pragma unroll
        for (int rr = 1; rr < 12; ++rr) {
            float4 v = red[rr * 21 + t];
            s.x += v.x; s.y += v.y; s.z += v.z; s.w += v.w;
        }
        atomicAdd(&part[t * 4 + 0], s.x);
        atomicAdd(&part[t * 4 + 1], s.y);
        atomicAdd(&part[t * 4 + 2], s.z);
        atomicAdd(&part[t * 4 + 3], s.w);
    }
}

// ---------------- tail MLP + log_softmax ----------------
__global__ __launch_bounds__(128) void fctail_kernel(const float* __restrict__ part,
                                                     const float* __restrict__ fc1_b,
                                                     const float* __restrict__ fc2_w,
                                                     const float* __restrict__ fc2_b,
                                                     const float* __restrict__ fc3_w,
                                                     const float* __restrict__ fc3_b,
                                                     float* __restrict__ out) {
    __shared__ float z1[84];
    __shared__ float z2[24];
    int t = threadIdx.x;
    if (t < 84) z1[t] = elu1(part[t] + fc1_b[t]);
    __syncthreads();
    if (t < 24) {
        float a = fc2_b[t];
        for (int i = 0; i < 84; ++i) a = fmaf(z1[i], fc2_w[i * 24 + t], a);
        z2[t] = elu1(a);
    }
    __syncthreads();
    if (t == 0) {
        float z3[2];
        #pragma unroll
        for (int jj = 0; jj < 2; ++jj) {
            float a = fc3_b[jj];
            for (int i = 0; i < 24; ++i) a = fmaf(z2[i], fc3_w[i * 2 + jj], a);
            z3[jj] = a;
        }
        float m = fmaxf(z3[0], z3[1]);
        float l = m + logf(__expf(z3[0] - m) + __expf(z3[1] - m));
        out[0] = z3[0] - l;
        out[1] = z3[1] - l;
    }
}

extern "C" void kernel_launch(void* const* d_in, const int* in_sizes, int n_in,
                              void* d_out, int out_size, void* d_ws, size_t ws_size,
                              hipStream_t stream) {
    const float* x        = (const float*)d_in[0];
    const int*   ei       = (const int*)d_in[1];
    const float* W1       = (const float*)d_in[2];
    const float* att_src1 = (const float*)d_in[3];
    const float* att_dst1 = (const float*)d_in[4];
    const float* b1       = (const float*)d_in[5];
    const float* W2       = (const float*)d_in[6];
    const float* att_src2 = (const float*)d_in[7];
    const float* att_dst2 = (const float*)d_in[8];
    const float* b2       = (const float*)d_in[9];
    const float* fc1_w    = (const float*)d_in[10];
    const float* fc1_b    = (const float*)d_in[11];
    const float* fc2_w    = (const float*)d_in[12];
    const float* fc2_b    = (const float*)d_in[13];
    const float* fc3_w    = (const float*)d_in[14];
    const float* fc3_b    = (const float*)d_in[15];
    float* out = (float*)d_out;

    char* ws = (char*)d_ws;
    unsigned int* h1b = (unsigned int*)(ws + 0);         // 12,800,000 B
    float* hbuf   = (float*)(ws + 12800000);             // 25,600,000 B
    float* a_src1 = (float*)(ws + 38400000);             // 1,600,000 B
    float* a_dst1 = (float*)(ws + 40000000);             // 1,600,000 B
    float* h2     = (float*)(ws + 41600000);             // 1,600,000 B
    float* a_src2 = (float*)(ws + 43200000);             // 200,000 B
    float* a_dst2 = (float*)(ws + 43400000);             // 200,000 B
    float* g      = (float*)(ws + 43600000);             // 1,600,000 B
    int*   counts = (int*)  (ws + 45200000);             // 200,000 B
    int*   rowptr = (int*)  (ws + 45400000);             // 200,004 B (padded)
    int*   cursor = (int*)  (ws + 45600192);             // 200,000 B
    int*   esrc   = (int*)  (ws + 45800192);             // 3,400,000 B
    float* part   = (float*)(ws + 49200192);             // 384 B
    int*   flag   = (int*)  (ws + 49200576);             // 4 B

    hipMemsetAsync(part, 0, 384, stream);

    detect_kernel<<<1, 64, 0, stream>>>(ei, flag);
    init_counts_kernel<<<(N_NODES + 255) / 256, 256, 0, stream>>>(counts);
    hist_kernel<<<(NE + 255) / 256, 256, 0, stream>>>(ei, flag, counts);
    scan_kernel<<<1, 1024, 0, stream>>>(counts, rowptr, cursor);
    fill_kernel<<<(NE + N_NODES + 255) / 256, 256, 0, stream>>>(ei, flag, cursor, esrc);

    gemm1_kernel<<<(N_NODES + 63) / 64, 256, 0, stream>>>(x, W1, att_src1, att_dst1, h1b, a_src1, a_dst1);
    agg1_kernel<<<(N_NODES + 3) / 4, 256, 0, stream>>>(h1b, a_src1, a_dst1, rowptr, esrc, b1, hbuf);

    gemm2_kernel<<<(N_NODES + 31) / 32, 256, 0, stream>>>(hbuf, W2, att_src2, att_dst2, h2, a_src2, a_dst2);
    agg2_kernel<<<(N_NODES + 255) / 256, 256, 0, stream>>>(h2, a_src2, a_dst2, rowptr, esrc, b2, g);

    fc1_kernel<<<2048, 256, 0, stream>>>(g, fc1_w, part);
    fctail_kernel<<<1, 128, 0, stream>>>(part, fc1_b, fc2_w, fc2_b, fc3_w, fc3_b, out);
}

// Round 4
// 319.434 us; speedup vs baseline: 1.3058x; 1.3058x over previous
//
#include <hip/hip_runtime.h>
#include <math.h>

#define N_NODES 50000
#define F_IN 128
#define NE 800000
#define NH1 8
#define ND1 16
#define ND2 8
#define NEG 0.2f

#define ZLEN (N_NODES * ND2)      // 400000
#define FC1_ROWS 196
#define FC1_BLOCKS 2041           // 2041*196 = 400036 >= 400000

__device__ __forceinline__ float lrelu(float v) { return v > 0.f ? v : NEG * v; }
__device__ __forceinline__ float elu1(float v)  { return v > 0.f ? v : (__expf(v) - 1.f); }

__device__ __forceinline__ unsigned short f2bf(float f) {
    union { float f; unsigned int i; } c; c.f = f;
    unsigned int u = c.i;
    return (unsigned short)((u + 0x7FFFu + ((u >> 16) & 1u)) >> 16);
}
__device__ __forceinline__ float bflo(unsigned int u) {
    union { unsigned int i; float f; } c; c.i = u << 16; return c.f;
}
__device__ __forceinline__ float bfhi(unsigned int u) {
    union { unsigned int i; float f; } c; c.i = u & 0xFFFF0000u; return c.f;
}

// ---------------- edge dtype detection (int32 vs int64) ----------------
__global__ void detect_kernel(const int* __restrict__ ei, int* __restrict__ flag) {
    if (blockIdx.x == 0 && threadIdx.x == 0) {
        int all0 = 1;
        for (int k = 0; k < 64; ++k) {
            if (ei[2 * k + 1] != 0) { all0 = 0; break; }
        }
        *flag = all0;   // 1 => data is int64 (high words zero), 0 => int32
    }
}

// ---------------- CSR build ----------------
__global__ void init_counts_kernel(int* __restrict__ counts) {
    int i = blockIdx.x * blockDim.x + threadIdx.x;
    if (i < N_NODES) counts[i] = 1;   // self-loop
}

__global__ void hist_kernel(const int* __restrict__ ei, const int* __restrict__ flag,
                            int* __restrict__ counts) {
    int e = blockIdx.x * blockDim.x + threadIdx.x;
    if (e >= NE) return;
    int is64 = *flag;
    int d = is64 ? ei[2 * NE + 2 * e] : ei[NE + e];
    atomicAdd(&counts[d], 1);
}

__global__ __launch_bounds__(1024) void scan_kernel(const int* __restrict__ counts,
                                                    int* __restrict__ rowptr,
                                                    int* __restrict__ cursor) {
    __shared__ int wsum[16];
    __shared__ int wpre[16];
    __shared__ int s_total;
    const int t = threadIdx.x;
    const int lane = t & 63, w = t >> 6;
    int carry = 0;
    if (t == 0) rowptr[0] = 0;
    for (int base = 0; base < N_NODES; base += 1024) {
        int i = base + t;
        int orig = (i < N_NODES) ? counts[i] : 0;
        int v = orig;
        #pragma unroll
        for (int off = 1; off < 64; off <<= 1) {
            int u = __shfl_up(v, off, 64);
            if (lane >= off) v += u;
        }
        if (lane == 63) wsum[w] = v;
        __syncthreads();
        if (t == 0) {
            int s = 0;
            #pragma unroll
            for (int j = 0; j < 16; ++j) { wpre[j] = s; s += wsum[j]; }
            s_total = s;
        }
        __syncthreads();
        int incl = v + wpre[w] + carry;
        if (i < N_NODES) { rowptr[i + 1] = incl; cursor[i] = incl - orig; }
        carry += s_total;
        __syncthreads();
    }
}

__global__ void fill_kernel(const int* __restrict__ ei, const int* __restrict__ flag,
                            int* __restrict__ cursor, int* __restrict__ esrc) {
    int i = blockIdx.x * blockDim.x + threadIdx.x;
    if (i >= NE + N_NODES) return;
    int is64 = *flag;
    int s, d;
    if (i < NE) {
        if (is64) { s = ei[2 * i]; d = ei[2 * NE + 2 * i]; }
        else      { s = ei[i];     d = ei[NE + i]; }
    } else {
        s = d = i - NE;
    }
    int slot = atomicAdd(&cursor[d], 1);
    esrc[slot] = s;
}

// ---------------- conv1 GEMM: h1 = x @ W1, fused attention scores, bf16 output ----------------
__global__ __launch_bounds__(256) void gemm1_kernel(const float* __restrict__ x,
                                                    const float* __restrict__ W,
                                                    const float* __restrict__ att_src,
                                                    const float* __restrict__ att_dst,
                                                    unsigned int* __restrict__ h1b,
                                                    float* __restrict__ a_src1,
                                                    float* __restrict__ a_dst1) {
    __shared__ float Ws[32 * 128];
    __shared__ float Xs[32 * 68];   // transposed x chunk, stride 68 (16B-aligned rows)
    const int t = threadIdx.x;
    const int cg = t & 31;          // col group -> cols cg*4..+3
    const int rg = t >> 5;          // row group -> rows rg*8..+7
    const int row0 = blockIdx.x * 64;

    float acc[8][4];
    #pragma unroll
    for (int i = 0; i < 8; ++i)
        #pragma unroll
        for (int j = 0; j < 4; ++j) acc[i][j] = 0.f;

    for (int kc = 0; kc < 4; ++kc) {
        // stage W chunk (32 x 128)
        #pragma unroll
        for (int i = 0; i < 4; ++i) {
            int fidx = i * 256 + t;
            const float4 wv = *reinterpret_cast<const float4*>(W + kc * 32 * 128 + fidx * 4);
            *reinterpret_cast<float4*>(&Ws[fidx * 4]) = wv;
        }
        // stage x chunk transposed: Xs[kk][r] = x[row0+r][kc*32+kk]
        {
            int r = t >> 2;
            int k4a = t & 3;
            int grow = row0 + r;
            #pragma unroll
            for (int p = 0; p < 2; ++p) {
                int k4 = k4a + p * 4;
                float4 xv = make_float4(0.f, 0.f, 0.f, 0.f);
                if (grow < N_NODES)
                    xv = *reinterpret_cast<const float4*>(x + grow * F_IN + kc * 32 + k4 * 4);
                Xs[(k4 * 4 + 0) * 68 + r] = xv.x;
                Xs[(k4 * 4 + 1) * 68 + r] = xv.y;
                Xs[(k4 * 4 + 2) * 68 + r] = xv.z;
                Xs[(k4 * 4 + 3) * 68 + r] = xv.w;
            }
        }
        __syncthreads();
        #pragma unroll
        for (int kk = 0; kk < 32; ++kk) {
            float4 wv = *reinterpret_cast<const float4*>(&Ws[kk * 128 + cg * 4]);
            float4 xa = *reinterpret_cast<const float4*>(&Xs[kk * 68 + rg * 8]);
            float4 xb = *reinterpret_cast<const float4*>(&Xs[kk * 68 + rg * 8 + 4]);
            float xr[8] = {xa.x, xa.y, xa.z, xa.w, xb.x, xb.y, xb.z, xb.w};
            float wr[4] = {wv.x, wv.y, wv.z, wv.w};
            #pragma unroll
            for (int i = 0; i < 8; ++i)
                #pragma unroll
                for (int j = 0; j < 4; ++j)
                    acc[i][j] = fmaf(xr[i], wr[j], acc[i][j]);
        }
        __syncthreads();
    }
    // epilogue: bf16 store + fused attention score partials
    const int h = cg >> 2;          // head 0..7
    const int q = cg & 3;           // quarter within head (dims 4q..4q+3)
    float as0 = att_src[h * ND1 + 4 * q + 0], as1 = att_src[h * ND1 + 4 * q + 1];
    float as2 = att_src[h * ND1 + 4 * q + 2], as3 = att_src[h * ND1 + 4 * q + 3];
    float ad0 = att_dst[h * ND1 + 4 * q + 0], ad1 = att_dst[h * ND1 + 4 * q + 1];
    float ad2 = att_dst[h * ND1 + 4 * q + 2], ad3 = att_dst[h * ND1 + 4 * q + 3];
    #pragma unroll
    for (int i = 0; i < 8; ++i) {
        int grow = row0 + rg * 8 + i;
        float ps = acc[i][0] * as0 + acc[i][1] * as1 + acc[i][2] * as2 + acc[i][3] * as3;
        float pd = acc[i][0] * ad0 + acc[i][1] * ad1 + acc[i][2] * ad2 + acc[i][3] * ad3;
        ps += __shfl_xor(ps, 1, 64); ps += __shfl_xor(ps, 2, 64);
        pd += __shfl_xor(pd, 1, 64); pd += __shfl_xor(pd, 2, 64);
        if (grow < N_NODES) {
            uint2 wv;
            wv.x = (unsigned int)f2bf(acc[i][0]) | ((unsigned int)f2bf(acc[i][1]) << 16);
            wv.y = (unsigned int)f2bf(acc[i][2]) | ((unsigned int)f2bf(acc[i][3]) << 16);
            *reinterpret_cast<uint2*>(h1b + (size_t)grow * 64 + cg * 2) = wv;
            if (q == 0) {
                a_src1[grow * 8 + h] = ps;
                a_dst1[grow * 8 + h] = pd;
            }
        }
    }
}

// ---------------- conv1 aggregation: one wave per dst node, bf16 gather ----------------
__global__ __launch_bounds__(256) void agg1_kernel(const unsigned int* __restrict__ h1b,
                                                   const float* __restrict__ a_src,
                                                   const float* __restrict__ a_dst,
                                                   const int* __restrict__ rowptr,
                                                   const int* __restrict__ esrc,
                                                   const float* __restrict__ b1,
                                                   float* __restrict__ hout) {
    int wid = (blockIdx.x * 256 + threadIdx.x) >> 6;   // node id (wave-uniform)
    if (wid >= N_NODES) return;
    const int lane = threadIdx.x & 63;
    const int h = lane >> 3;                            // head for this lane's 2 dims
    const float ad = a_dst[wid * 8 + h];
    float acc0 = 0.f, acc1 = 0.f, den = 0.f;
    int j = rowptr[wid];
    const int jend = rowptr[wid + 1];
    for (; j + 4 <= jend; j += 4) {
        int s0 = esrc[j], s1 = esrc[j + 1], s2 = esrc[j + 2], s3 = esrc[j + 3];
        float e0 = a_src[s0 * 8 + h], e1 = a_src[s1 * 8 + h];
        float e2 = a_src[s2 * 8 + h], e3 = a_src[s3 * 8 + h];
        unsigned int u0 = h1b[(size_t)s0 * 64 + lane];
        unsigned int u1 = h1b[(size_t)s1 * 64 + lane];
        unsigned int u2 = h1b[(size_t)s2 * 64 + lane];
        unsigned int u3 = h1b[(size_t)s3 * 64 + lane];
        float p0 = __expf(lrelu(e0 + ad));
        float p1 = __expf(lrelu(e1 + ad));
        float p2 = __expf(lrelu(e2 + ad));
        float p3 = __expf(lrelu(e3 + ad));
        den += (p0 + p1) + (p2 + p3);
        acc0 = fmaf(p0, bflo(u0), acc0); acc1 = fmaf(p0, bfhi(u0), acc1);
        acc0 = fmaf(p1, bflo(u1), acc0); acc1 = fmaf(p1, bfhi(u1), acc1);
        acc0 = fmaf(p2, bflo(u2), acc0); acc1 = fmaf(p2, bfhi(u2), acc1);
        acc0 = fmaf(p3, bflo(u3), acc0); acc1 = fmaf(p3, bfhi(u3), acc1);
    }
    for (; j < jend; ++j) {
        int s = esrc[j];
        float e = a_src[s * 8 + h];
        unsigned int u = h1b[(size_t)s * 64 + lane];
        float p = __expf(lrelu(e + ad));
        den += p;
        acc0 = fmaf(p, bflo(u), acc0);
        acc1 = fmaf(p, bfhi(u), acc1);
    }
    float inv = 1.f / den;
    float2 bb = *reinterpret_cast<const float2*>(b1 + 2 * lane);
    float o0 = elu1(acc0 * inv + bb.x);
    float o1 = elu1(acc1 * inv + bb.y);
    *reinterpret_cast<float2*>(hout + (size_t)wid * F_IN + 2 * lane) = make_float2(o0, o1);
}

// ---------------- conv2 GEMM + attention scores ----------------
__global__ __launch_bounds__(256) void gemm2_kernel(const float* __restrict__ h,
                                                    const float* __restrict__ W2,
                                                    const float* __restrict__ att_src2,
                                                    const float* __restrict__ att_dst2,
                                                    float* __restrict__ h2,
                                                    float* __restrict__ a_src2,
                                                    float* __restrict__ a_dst2) {
    __shared__ float Ws[F_IN * ND2];     // 4 KB
    __shared__ float Hs[32 * 132];       // padded, ~16.9 KB
    int t = threadIdx.x;
    int node0 = blockIdx.x * 32;
    #pragma unroll
    for (int i = 0; i < 4; ++i) { int idx = i * 256 + t; Ws[idx] = W2[idx]; }
    #pragma unroll
    for (int i = 0; i < 4; ++i) {
        int fidx = i * 256 + t;
        int r = fidx >> 5;
        int c4 = fidx & 31;
        int grow = node0 + r;
        float4 v = make_float4(0.f, 0.f, 0.f, 0.f);
        if (grow < N_NODES) v = *reinterpret_cast<const float4*>(h + (size_t)grow * F_IN + c4 * 4);
        *reinterpret_cast<float4*>(&Hs[r * 132 + c4 * 4]) = v;
    }
    __syncthreads();
    int nsub = t >> 3, d = t & 7;
    int node = node0 + nsub;
    float acc = 0.f;
    #pragma unroll 8
    for (int k = 0; k < F_IN; ++k)
        acc = fmaf(Hs[nsub * 132 + k], Ws[k * ND2 + d], acc);
    float vs = acc * att_src2[d];
    float vd = acc * att_dst2[d];
    #pragma unroll
    for (int off = 4; off >= 1; off >>= 1) {
        vs += __shfl_xor(vs, off, 8);
        vd += __shfl_xor(vd, off, 8);
    }
    if (node < N_NODES) {
        h2[node * ND2 + d] = acc;
        if (d == 0) { a_src2[node] = vs; a_dst2[node] = vd; }
    }
}

// ---------------- conv2 aggregation: one thread per node ----------------
__global__ void agg2_kernel(const float* __restrict__ h2,
                            const float* __restrict__ a_src2, const float* __restrict__ a_dst2,
                            const int* __restrict__ rowptr, const int* __restrict__ esrc,
                            const float* __restrict__ b2, float* __restrict__ g) {
    int n = blockIdx.x * blockDim.x + threadIdx.x;
    if (n >= N_NODES) return;
    float ad = a_dst2[n];
    float acc[8] = {0.f, 0.f, 0.f, 0.f, 0.f, 0.f, 0.f, 0.f};
    float den = 0.f;
    int jend = rowptr[n + 1];
    for (int j = rowptr[n]; j < jend; ++j) {
        int s = esrc[j];
        float p = __expf(lrelu(a_src2[s] + ad));
        den += p;
        float4 va = *reinterpret_cast<const float4*>(h2 + s * ND2);
        float4 vb = *reinterpret_cast<const float4*>(h2 + s * ND2 + 4);
        acc[0] = fmaf(p, va.x, acc[0]); acc[1] = fmaf(p, va.y, acc[1]);
        acc[2] = fmaf(p, va.z, acc[2]); acc[3] = fmaf(p, va.w, acc[3]);
        acc[4] = fmaf(p, vb.x, acc[4]); acc[5] = fmaf(p, vb.y, acc[5]);
        acc[6] = fmaf(p, vb.z, acc[6]); acc[7] = fmaf(p, vb.w, acc[7]);
    }
    float inv = 1.f / den;
    float4 o0 = make_float4(elu1(acc[0] * inv + b2[0]), elu1(acc[1] * inv + b2[1]),
                            elu1(acc[2] * inv + b2[2]), elu1(acc[3] * inv + b2[3]));
    float4 o1 = make_float4(elu1(acc[4] * inv + b2[4]), elu1(acc[5] * inv + b2[5]),
                            elu1(acc[6] * inv + b2[6]), elu1(acc[7] * inv + b2[7]));
    *reinterpret_cast<float4*>(g + n * ND2)     = o0;
    *reinterpret_cast<float4*>(g + n * ND2 + 4) = o1;
}

// ---------------- fc1 stage 1: per-block partial sums, contiguous chunks, no atomics ----
// Block b owns rows [b*196, b*196+196). z chunk staged in LDS. Threads: 21 float4-cols
// x 12 rows; 4 groups of 4 independent float4 loads each; partial[b][88] written coalesced.
__global__ __launch_bounds__(256) void fc1_stage1(const float* __restrict__ z,
                                                  const float* __restrict__ w,
                                                  float* __restrict__ partial) {
    __shared__ float zs[FC1_ROWS];
    __shared__ float4 red[252];
    const int t = threadIdx.x;
    const int b = blockIdx.x;
    const int r0 = b * FC1_ROWS;
    if (t < FC1_ROWS) {
        int gr = r0 + t;
        zs[t] = (gr < ZLEN) ? z[gr] : 0.f;
    }
    __syncthreads();
    const int c4 = t % 21;
    const int rr = t / 21;          // 0..11 for active threads
    float4 acc = make_float4(0.f, 0.f, 0.f, 0.f);
    if (t < 252) {
        const float4* __restrict__ w4 = reinterpret_cast<const float4*>(w);
        #pragma unroll
        for (int gq = 0; gq < 4; ++gq) {
            float4 wv[4];
            float  zv[4];
            #pragma unroll
            for (int u = 0; u < 4; ++u) {
                int rl = gq * 48 + u * 12 + rr;          // < 192
                int gr = r0 + rl;
                wv[u] = (gr < ZLEN) ? w4[(size_t)gr * 21 + c4]
                                    : make_float4(0.f, 0.f, 0.f, 0.f);
                zv[u] = zs[rl];
            }
            #pragma unroll
            for (int u = 0; u < 4; ++u) {
                acc.x = fmaf(zv[u], wv[u].x, acc.x);
                acc.y = fmaf(zv[u], wv[u].y, acc.y);
                acc.z = fmaf(zv[u], wv[u].z, acc.z);
                acc.w = fmaf(zv[u], wv[u].w, acc.w);
            }
        }
        // tail rows 192..195
        if (rr < 4) {
            int rl = 192 + rr;
            int gr = r0 + rl;
            if (gr < ZLEN) {
                float4 wv = w4[(size_t)gr * 21 + c4];
                float  zv = zs[rl];
                acc.x = fmaf(zv, wv.x, acc.x);
                acc.y = fmaf(zv, wv.y, acc.y);
                acc.z = fmaf(zv, wv.z, acc.z);
                acc.w = fmaf(zv, wv.w, acc.w);
            }
        }
        red[t] = acc;
    }
    __syncthreads();
    if (t < 21) {
        float4 s = red[t];
        #pragma unroll
        for (int k = 1; k < 12; ++k) {
            float4 v = red[k * 21 + t];
            s.x += v.x; s.y += v.y; s.z += v.z; s.w += v.w;
        }
        *reinterpret_cast<float4*>(partial + (size_t)b * 88 + t * 4) = s;
    }
}

// ---------------- fc1 stage 2: reduce partials (no atomics) ----------------
__global__ __launch_bounds__(256) void fc1_stage2(const float* __restrict__ partial,
                                                  float* __restrict__ part) {
    __shared__ float red[252];
    const int t = threadIdx.x;
    if (t < 252) {
        const int j = t % 84;
        const int slice = t / 84;       // 0..2
        const int b0 = (slice == 0) ? 0 : (slice == 1 ? 681 : 1361);
        const int b1 = (slice == 0) ? 681 : (slice == 1 ? 1361 : FC1_BLOCKS);
        float s = 0.f;
        int b = b0;
        for (; b + 4 <= b1; b += 4) {
            float v0 = partial[(size_t)(b + 0) * 88 + j];
            float v1 = partial[(size_t)(b + 1) * 88 + j];
            float v2 = partial[(size_t)(b + 2) * 88 + j];
            float v3 = partial[(size_t)(b + 3) * 88 + j];
            s += (v0 + v1) + (v2 + v3);
        }
        for (; b < b1; ++b) s += partial[(size_t)b * 88 + j];
        red[t] = s;
    }
    __syncthreads();
    if (t < 84) part[t] = red[t] + red[t + 84] + red[t + 168];
}

// ---------------- tail MLP + log_softmax ----------------
__global__ __launch_bounds__(128) void fctail_kernel(const float* __restrict__ part,
                                                     const float* __restrict__ fc1_b,
                                                     const float* __restrict__ fc2_w,
                                                     const float* __restrict__ fc2_b,
                                                     const float* __restrict__ fc3_w,
                                                     const float* __restrict__ fc3_b,
                                                     float* __restrict__ out) {
    __shared__ float z1[84];
    __shared__ float z2[24];
    int t = threadIdx.x;
    if (t < 84) z1[t] = elu1(part[t] + fc1_b[t]);
    __syncthreads();
    if (t < 24) {
        float a = fc2_b[t];
        for (int i = 0; i < 84; ++i) a = fmaf(z1[i], fc2_w[i * 24 + t], a);
        z2[t] = elu1(a);
    }
    __syncthreads();
    if (t == 0) {
        float z3[2];
        #pragma unroll
        for (int jj = 0; jj < 2; ++jj) {
            float a = fc3_b[jj];
            for (int i = 0; i < 24; ++i) a = fmaf(z2[i], fc3_w[i * 2 + jj], a);
            z3[jj] = a;
        }
        float m = fmaxf(z3[0], z3[1]);
        float l = m + logf(__expf(z3[0] - m) + __expf(z3[1] - m));
        out[0] = z3[0] - l;
        out[1] = z3[1] - l;
    }
}

extern "C" void kernel_launch(void* const* d_in, const int* in_sizes, int n_in,
                              void* d_out, int out_size, void* d_ws, size_t ws_size,
                              hipStream_t stream) {
    const float* x        = (const float*)d_in[0];
    const int*   ei       = (const int*)d_in[1];
    const float* W1       = (const float*)d_in[2];
    const float* att_src1 = (const float*)d_in[3];
    const float* att_dst1 = (const float*)d_in[4];
    const float* b1       = (const float*)d_in[5];
    const float* W2       = (const float*)d_in[6];
    const float* att_src2 = (const float*)d_in[7];
    const float* att_dst2 = (const float*)d_in[8];
    const float* b2       = (const float*)d_in[9];
    const float* fc1_w    = (const float*)d_in[10];
    const float* fc1_b    = (const float*)d_in[11];
    const float* fc2_w    = (const float*)d_in[12];
    const float* fc2_b    = (const float*)d_in[13];
    const float* fc3_w    = (const float*)d_in[14];
    const float* fc3_b    = (const float*)d_in[15];
    float* out = (float*)d_out;

    char* ws = (char*)d_ws;
    unsigned int* h1b = (unsigned int*)(ws + 0);         // 12,800,000 B
    float* hbuf   = (float*)(ws + 12800000);             // 25,600,000 B
    float* a_src1 = (float*)(ws + 38400000);             // 1,600,000 B
    float* a_dst1 = (float*)(ws + 40000000);             // 1,600,000 B
    float* h2     = (float*)(ws + 41600000);             // 1,600,000 B
    float* a_src2 = (float*)(ws + 43200000);             // 200,000 B
    float* a_dst2 = (float*)(ws + 43400000);             // 200,000 B
    float* g      = (float*)(ws + 43600000);             // 1,600,000 B
    int*   counts = (int*)  (ws + 45200000);             // 200,000 B
    int*   rowptr = (int*)  (ws + 45400000);             // 200,004 B (padded)
    int*   cursor = (int*)  (ws + 45600192);             // 200,000 B
    int*   esrc   = (int*)  (ws + 45800192);             // 3,400,000 B
    float* part   = (float*)(ws + 49200192);             // 384 B
    int*   flag   = (int*)  (ws + 49200576);             // 4 B (+pad)
    float* partial= (float*)(ws + 49200592);             // 2041*88*4 = 718,432 B

    detect_kernel<<<1, 64, 0, stream>>>(ei, flag);
    init_counts_kernel<<<(N_NODES + 255) / 256, 256, 0, stream>>>(counts);
    hist_kernel<<<(NE + 255) / 256, 256, 0, stream>>>(ei, flag, counts);
    scan_kernel<<<1, 1024, 0, stream>>>(counts, rowptr, cursor);
    fill_kernel<<<(NE + N_NODES + 255) / 256, 256, 0, stream>>>(ei, flag, cursor, esrc);

    gemm1_kernel<<<(N_NODES + 63) / 64, 256, 0, stream>>>(x, W1, att_src1, att_dst1, h1b, a_src1, a_dst1);
    agg1_kernel<<<(N_NODES + 3) / 4, 256, 0, stream>>>(h1b, a_src1, a_dst1, rowptr, esrc, b1, hbuf);

    gemm2_kernel<<<(N_NODES + 31) / 32, 256, 0, stream>>>(hbuf, W2, att_src2, att_dst2, h2, a_src2, a_dst2);
    agg2_kernel<<<(N_NODES + 255) / 256, 256, 0, stream>>>(h2, a_src2, a_dst2, rowptr, esrc, b2, g);

    fc1_stage1<<<FC1_BLOCKS, 256, 0, stream>>>(g, fc1_w, partial);
    fc1_stage2<<<1, 256, 0, stream>>>(partial, part);
    fctail_kernel<<<1, 128, 0, stream>>>(part, fc1_b, fc2_w, fc2_b, fc3_w, fc3_b, out);
}

// Round 5
// 273.942 us; speedup vs baseline: 1.5226x; 1.1661x over previous
//
#include <hip/hip_runtime.h>
#include <math.h>

#define N_NODES 50000
#define F_IN 128
#define NE 800000
#define NH1 8
#define ND1 16
#define ND2 8
#define NEG 0.2f
#define ZLEN (N_NODES * ND2)      // 400000

typedef __attribute__((ext_vector_type(8))) short bf16x8;   // 8 bf16 (4 VGPRs)
typedef __attribute__((ext_vector_type(4))) float f32x4;

__device__ __forceinline__ float lrelu(float v) { return v > 0.f ? v : NEG * v; }
__device__ __forceinline__ float elu1(float v)  { return v > 0.f ? v : (__expf(v) - 1.f); }

__device__ __forceinline__ unsigned short f2bf(float f) {
    union { float f; unsigned int i; } c; c.f = f;
    unsigned int u = c.i;
    return (unsigned short)((u + 0x7FFFu + ((u >> 16) & 1u)) >> 16);
}
__device__ __forceinline__ float bflo(unsigned int u) {
    union { unsigned int i; float f; } c; c.i = u << 16; return c.f;
}
__device__ __forceinline__ float bfhi(unsigned int u) {
    union { unsigned int i; float f; } c; c.i = u & 0xFFFF0000u; return c.f;
}
// int64-vs-int32 edge dtype: high words of first 4 entries all zero => int64
__device__ __forceinline__ int ei_is64(const int* __restrict__ ei) {
    return ((ei[1] | ei[3] | ei[5] | ei[7]) == 0) ? 1 : 0;
}

// ---------------- CSR build ----------------
__global__ void init_counts_kernel(int* __restrict__ counts) {
    int i = blockIdx.x * blockDim.x + threadIdx.x;
    if (i < N_NODES) counts[i] = 1;   // self-loop
}

__global__ void hist_kernel(const int* __restrict__ ei, int* __restrict__ counts) {
    int e = blockIdx.x * blockDim.x + threadIdx.x;
    if (e >= NE) return;
    int is64 = ei_is64(ei);
    int d = is64 ? ei[2 * NE + 2 * e] : ei[NE + e];
    atomicAdd(&counts[d], 1);
}

__global__ __launch_bounds__(1024) void scan_kernel(const int* __restrict__ counts,
                                                    int* __restrict__ rowptr,
                                                    int* __restrict__ cursor) {
    __shared__ int wsum[16];
    __shared__ int wpre[16];
    __shared__ int s_total;
    const int t = threadIdx.x;
    const int lane = t & 63, w = t >> 6;
    int carry = 0;
    if (t == 0) rowptr[0] = 0;
    for (int base = 0; base < N_NODES; base += 1024) {
        int i = base + t;
        int orig = (i < N_NODES) ? counts[i] : 0;
        int v = orig;
        #pragma unroll
        for (int off = 1; off < 64; off <<= 1) {
            int u = __shfl_up(v, off, 64);
            if (lane >= off) v += u;
        }
        if (lane == 63) wsum[w] = v;
        __syncthreads();
        if (t == 0) {
            int s = 0;
            #pragma unroll
            for (int j = 0; j < 16; ++j) { wpre[j] = s; s += wsum[j]; }
            s_total = s;
        }
        __syncthreads();
        int incl = v + wpre[w] + carry;
        if (i < N_NODES) { rowptr[i + 1] = incl; cursor[i] = incl - orig; }
        carry += s_total;
        __syncthreads();
    }
}

__global__ void fill_kernel(const int* __restrict__ ei,
                            int* __restrict__ cursor, int* __restrict__ esrc) {
    int i = blockIdx.x * blockDim.x + threadIdx.x;
    if (i >= NE + N_NODES) return;
    int s, d;
    if (i < NE) {
        int is64 = ei_is64(ei);
        if (is64) { s = ei[2 * i]; d = ei[2 * NE + 2 * i]; }
        else      { s = ei[i];     d = ei[NE + i]; }
    } else {
        s = d = i - NE;
    }
    int slot = atomicAdd(&cursor[d], 1);
    esrc[slot] = s;
}

// ---------------- W1 prep: bf16, transposed [col][k], chunk-XOR-swizzled ----------------
// dst chunk (8 bf16 = uint4) index: col*16 + ((k>>3) ^ (col&15))
__global__ __launch_bounds__(256) void wprep_kernel(const float* __restrict__ W,
                                                    uint4* __restrict__ wbf) {
    int tid = blockIdx.x * 256 + threadIdx.x;   // 0..2047
    int col = tid >> 4, kc = tid & 15;
    unsigned int u[4];
    #pragma unroll
    for (int jj = 0; jj < 4; ++jj) {
        unsigned int lo = f2bf(W[(kc * 8 + 2 * jj) * 128 + col]);
        unsigned int hi = f2bf(W[(kc * 8 + 2 * jj + 1) * 128 + col]);
        u[jj] = lo | (hi << 16);
    }
    uint4 v; v.x = u[0]; v.y = u[1]; v.z = u[2]; v.w = u[3];
    wbf[col * 16 + (kc ^ (col & 15))] = v;
}

// ---------------- conv1 GEMM via MFMA: h1 = x @ W1, fused att scores, bf16 packed out ----
// Block = 4 waves, 64 rows. Wave w: rows row0+w*16 .. +15, all 128 cols (8 tiles).
// D layout (m89-verified): col = lane&15, row = (lane>>4)*4 + reg.
__global__ __launch_bounds__(256) void gemm1_kernel(const float* __restrict__ x,
                                                    const uint4* __restrict__ wbf,
                                                    const float* __restrict__ att_src,
                                                    const float* __restrict__ att_dst,
                                                    unsigned int* __restrict__ h1b,
                                                    float* __restrict__ a_src1,
                                                    float* __restrict__ a_dst1) {
    __shared__ uint4 Xs[1024];   // 64 rows x 16 chunks (swizzled), 16 KB
    __shared__ uint4 Ws[2048];   // 128 cols x 16 chunks (pre-swizzled), 32 KB
    const int t = threadIdx.x;
    const int row0 = blockIdx.x * 64;

    // stage W (verbatim copy of pre-swizzled global)
    #pragma unroll
    for (int p = 0; p < 8; ++p) Ws[p * 256 + t] = wbf[p * 256 + t];

    // stage X: chunk cidx -> (row, c); swizzled write Xs[row*16 + (c ^ (row&15))]
    #pragma unroll
    for (int p = 0; p < 4; ++p) {
        int cidx = p * 256 + t;
        int row = cidx >> 4, c = cidx & 15;
        int grow = row0 + row;
        float4 xa = make_float4(0.f, 0.f, 0.f, 0.f);
        float4 xb = make_float4(0.f, 0.f, 0.f, 0.f);
        if (grow < N_NODES) {
            xa = *reinterpret_cast<const float4*>(x + (size_t)grow * F_IN + c * 8);
            xb = *reinterpret_cast<const float4*>(x + (size_t)grow * F_IN + c * 8 + 4);
        }
        uint4 u;
        u.x = (unsigned int)f2bf(xa.x) | ((unsigned int)f2bf(xa.y) << 16);
        u.y = (unsigned int)f2bf(xa.z) | ((unsigned int)f2bf(xa.w) << 16);
        u.z = (unsigned int)f2bf(xb.x) | ((unsigned int)f2bf(xb.y) << 16);
        u.w = (unsigned int)f2bf(xb.z) | ((unsigned int)f2bf(xb.w) << 16);
        Xs[row * 16 + (c ^ (row & 15))] = u;
    }
    __syncthreads();

    const int wv = t >> 6;
    const int l  = t & 63;
    const int d  = l & 15;      // col-within-tile / A row-within-tile
    const int g  = l >> 4;      // k-block group; also row-quad selector of D
    const int arow = wv * 16 + d;

    f32x4 acc[8];
    #pragma unroll
    for (int n = 0; n < 8; ++n) { acc[n][0] = 0.f; acc[n][1] = 0.f; acc[n][2] = 0.f; acc[n][3] = 0.f; }

    #pragma unroll
    for (int ks = 0; ks < 4; ++ks) {
        int kc = ks * 4 + g;
        union { uint4 u; bf16x8 v; } A;
        A.u = Xs[arow * 16 + (kc ^ d)];
        #pragma unroll
        for (int n = 0; n < 8; ++n) {
            union { uint4 u; bf16x8 v; } B;
            B.u = Ws[(n * 16 + d) * 16 + (kc ^ d)];
            acc[n] = __builtin_amdgcn_mfma_f32_16x16x32_bf16(A.v, B.v, acc[n], 0, 0, 0);
        }
    }

    // attention scores: head == tile n; reduce over the 16 lanes of each group
    float as8[8], ad8[8];
    #pragma unroll
    for (int n = 0; n < 8; ++n) { as8[n] = att_src[n * 16 + d]; ad8[n] = att_dst[n * 16 + d]; }
    #pragma unroll
    for (int n = 0; n < 8; ++n) {
        #pragma unroll
        for (int r = 0; r < 4; ++r) {
            float ps = acc[n][r] * as8[n];
            float pd = acc[n][r] * ad8[n];
            #pragma unroll
            for (int off = 1; off < 16; off <<= 1) {
                ps += __shfl_xor(ps, off, 16);
                pd += __shfl_xor(pd, off, 16);
            }
            int grow = row0 + wv * 16 + g * 4 + r;
            if (d == 0 && grow < N_NODES) {
                a_src1[grow * 8 + n] = ps;
                a_dst1[grow * 8 + n] = pd;
            }
        }
    }
    // packed bf16 store: h1b[node*64 + col/2] = (bf16(col+1)<<16) | bf16(col)
    #pragma unroll
    for (int n = 0; n < 8; ++n) {
        #pragma unroll
        for (int r = 0; r < 4; ++r) {
            float lo = acc[n][r];
            float hi = __shfl_xor(lo, 1, 64);
            int grow = row0 + wv * 16 + g * 4 + r;
            if (((d & 1) == 0) && grow < N_NODES) {
                unsigned int u = (unsigned int)f2bf(lo) | ((unsigned int)f2bf(hi) << 16);
                h1b[(size_t)grow * 64 + n * 8 + (d >> 1)] = u;
            }
        }
    }
}

// ---------------- conv1 aggregation: one wave per dst node, bf16 gather ----------------
__global__ __launch_bounds__(256) void agg1_kernel(const unsigned int* __restrict__ h1b,
                                                   const float* __restrict__ a_src,
                                                   const float* __restrict__ a_dst,
                                                   const int* __restrict__ rowptr,
                                                   const int* __restrict__ esrc,
                                                   const float* __restrict__ b1,
                                                   float* __restrict__ hout) {
    int wid = (blockIdx.x * 256 + threadIdx.x) >> 6;   // node id (wave-uniform)
    if (wid >= N_NODES) return;
    const int lane = threadIdx.x & 63;
    const int h = lane >> 3;                            // head for this lane's 2 dims
    const float ad = a_dst[wid * 8 + h];
    float acc0 = 0.f, acc1 = 0.f, den = 0.f;
    int j = rowptr[wid];
    const int jend = rowptr[wid + 1];
    for (; j + 4 <= jend; j += 4) {
        int s0 = esrc[j], s1 = esrc[j + 1], s2 = esrc[j + 2], s3 = esrc[j + 3];
        float e0 = a_src[s0 * 8 + h], e1 = a_src[s1 * 8 + h];
        float e2 = a_src[s2 * 8 + h], e3 = a_src[s3 * 8 + h];
        unsigned int u0 = h1b[(size_t)s0 * 64 + lane];
        unsigned int u1 = h1b[(size_t)s1 * 64 + lane];
        unsigned int u2 = h1b[(size_t)s2 * 64 + lane];
        unsigned int u3 = h1b[(size_t)s3 * 64 + lane];
        float p0 = __expf(lrelu(e0 + ad));
        float p1 = __expf(lrelu(e1 + ad));
        float p2 = __expf(lrelu(e2 + ad));
        float p3 = __expf(lrelu(e3 + ad));
        den += (p0 + p1) + (p2 + p3);
        acc0 = fmaf(p0, bflo(u0), acc0); acc1 = fmaf(p0, bfhi(u0), acc1);
        acc0 = fmaf(p1, bflo(u1), acc0); acc1 = fmaf(p1, bfhi(u1), acc1);
        acc0 = fmaf(p2, bflo(u2), acc0); acc1 = fmaf(p2, bfhi(u2), acc1);
        acc0 = fmaf(p3, bflo(u3), acc0); acc1 = fmaf(p3, bfhi(u3), acc1);
    }
    for (; j < jend; ++j) {
        int s = esrc[j];
        float e = a_src[s * 8 + h];
        unsigned int u = h1b[(size_t)s * 64 + lane];
        float p = __expf(lrelu(e + ad));
        den += p;
        acc0 = fmaf(p, bflo(u), acc0);
        acc1 = fmaf(p, bfhi(u), acc1);
    }
    float inv = 1.f / den;
    float2 bb = *reinterpret_cast<const float2*>(b1 + 2 * lane);
    float o0 = elu1(acc0 * inv + bb.x);
    float o1 = elu1(acc1 * inv + bb.y);
    *reinterpret_cast<float2*>(hout + (size_t)wid * F_IN + 2 * lane) = make_float2(o0, o1);
}

// ---------------- conv2 GEMM + attention scores ----------------
__global__ __launch_bounds__(256) void gemm2_kernel(const float* __restrict__ h,
                                                    const float* __restrict__ W2,
                                                    const float* __restrict__ att_src2,
                                                    const float* __restrict__ att_dst2,
                                                    float* __restrict__ h2,
                                                    float* __restrict__ a_src2,
                                                    float* __restrict__ a_dst2) {
    __shared__ float Ws[F_IN * ND2];     // 4 KB
    __shared__ float Hs[32 * 132];       // padded, ~16.9 KB
    int t = threadIdx.x;
    int node0 = blockIdx.x * 32;
    #pragma unroll
    for (int i = 0; i < 4; ++i) { int idx = i * 256 + t; Ws[idx] = W2[idx]; }
    #pragma unroll
    for (int i = 0; i < 4; ++i) {
        int fidx = i * 256 + t;
        int r = fidx >> 5;
        int c4 = fidx & 31;
        int grow = node0 + r;
        float4 v = make_float4(0.f, 0.f, 0.f, 0.f);
        if (grow < N_NODES) v = *reinterpret_cast<const float4*>(h + (size_t)grow * F_IN + c4 * 4);
        *reinterpret_cast<float4*>(&Hs[r * 132 + c4 * 4]) = v;
    }
    __syncthreads();
    int nsub = t >> 3, d = t & 7;
    int node = node0 + nsub;
    float acc = 0.f;
    #pragma unroll 8
    for (int k = 0; k < F_IN; ++k)
        acc = fmaf(Hs[nsub * 132 + k], Ws[k * ND2 + d], acc);
    float vs = acc * att_src2[d];
    float vd = acc * att_dst2[d];
    #pragma unroll
    for (int off = 4; off >= 1; off >>= 1) {
        vs += __shfl_xor(vs, off, 8);
        vd += __shfl_xor(vd, off, 8);
    }
    if (node < N_NODES) {
        h2[node * ND2 + d] = acc;
        if (d == 0) { a_src2[node] = vs; a_dst2[node] = vd; }
    }
}

// ---------------- conv2 aggregation FUSED with fc1 partial ----------------
// Phase 1: thread t computes node n = b*256+t: z[8] (GAT aggregation + elu) -> LDS.
// Phase 2: block streams its contiguous w slice rows [b*2048, b*2048+2048):
//          threads (c4 = t%21, rr = t/21), 5-deep independent float4 loads.
__global__ __launch_bounds__(256) void agg2fc1_kernel(const float* __restrict__ h2,
                                                      const float* __restrict__ a_src2,
                                                      const float* __restrict__ a_dst2,
                                                      const int* __restrict__ rowptr,
                                                      const int* __restrict__ esrc,
                                                      const float* __restrict__ b2,
                                                      const float* __restrict__ w,
                                                      float* __restrict__ partial) {
    __shared__ float zs[2048];
    __shared__ float4 red[252];
    const int t = threadIdx.x;
    const int n = blockIdx.x * 256 + t;

    float z[8] = {0.f, 0.f, 0.f, 0.f, 0.f, 0.f, 0.f, 0.f};
    if (n < N_NODES) {
        float ad = a_dst2[n];
        float den = 0.f;
        const int jend = rowptr[n + 1];
        for (int j = rowptr[n]; j < jend; ++j) {
            int s = esrc[j];
            float p = __expf(lrelu(a_src2[s] + ad));
            den += p;
            float4 va = *reinterpret_cast<const float4*>(h2 + s * ND2);
            float4 vb = *reinterpret_cast<const float4*>(h2 + s * ND2 + 4);
            z[0] = fmaf(p, va.x, z[0]); z[1] = fmaf(p, va.y, z[1]);
            z[2] = fmaf(p, va.z, z[2]); z[3] = fmaf(p, va.w, z[3]);
            z[4] = fmaf(p, vb.x, z[4]); z[5] = fmaf(p, vb.y, z[5]);
            z[6] = fmaf(p, vb.z, z[6]); z[7] = fmaf(p, vb.w, z[7]);
        }
        float inv = 1.f / den;
        #pragma unroll
        for (int k = 0; k < 8; ++k) z[k] = elu1(z[k] * inv + b2[k]);
    }
    *reinterpret_cast<float4*>(&zs[t * 8])     = make_float4(z[0], z[1], z[2], z[3]);
    *reinterpret_cast<float4*>(&zs[t * 8 + 4]) = make_float4(z[4], z[5], z[6], z[7]);
    __syncthreads();

    const int c4 = t % 21;
    const int rr = t / 21;
    if (t < 252) {
        float4 a = make_float4(0.f, 0.f, 0.f, 0.f);
        const float4* __restrict__ w4 = reinterpret_cast<const float4*>(w);
        const size_t R0 = (size_t)blockIdx.x * 2048;
        if (R0 + 2048 <= (size_t)ZLEN) {
            for (int gq = 0; gq < 34; ++gq) {
                float4 wv[5];
                float  zv[5];
                #pragma unroll
                for (int u = 0; u < 5; ++u) {
                    int i = (gq * 5 + u) * 12 + rr;
                    wv[u] = w4[(R0 + i) * 21 + c4];
                    zv[u] = zs[i];
                }
                #pragma unroll
                for (int u = 0; u < 5; ++u) {
                    a.x = fmaf(zv[u], wv[u].x, a.x);
                    a.y = fmaf(zv[u], wv[u].y, a.y);
                    a.z = fmaf(zv[u], wv[u].z, a.z);
                    a.w = fmaf(zv[u], wv[u].w, a.w);
                }
            }
            if (rr < 8) {   // tail rows 2040..2047
                int i = 2040 + rr;
                float4 wv = w4[(R0 + i) * 21 + c4];
                float  zv = zs[i];
                a.x = fmaf(zv, wv.x, a.x); a.y = fmaf(zv, wv.y, a.y);
                a.z = fmaf(zv, wv.z, a.z); a.w = fmaf(zv, wv.w, a.w);
            }
        } else {
            for (int i = rr; i < 2048; i += 12) {
                if (R0 + i < (size_t)ZLEN) {
                    float4 wv = w4[(R0 + i) * 21 + c4];
                    float  zv = zs[i];
                    a.x = fmaf(zv, wv.x, a.x); a.y = fmaf(zv, wv.y, a.y);
                    a.z = fmaf(zv, wv.z, a.z); a.w = fmaf(zv, wv.w, a.w);
                }
            }
        }
        red[t] = a;
    }
    __syncthreads();
    if (t < 21) {
        float4 s = red[t];
        #pragma unroll
        for (int k = 1; k < 12; ++k) {
            float4 v = red[k * 21 + t];
            s.x += v.x; s.y += v.y; s.z += v.z; s.w += v.w;
        }
        *reinterpret_cast<float4*>(partial + (size_t)blockIdx.x * 88 + t * 4) = s;
    }
}

// ---------------- tail: reduce partials + MLP + log_softmax ----------------
__global__ __launch_bounds__(256) void fctail_kernel(const float* __restrict__ partial,
                                                     const float* __restrict__ fc1_b,
                                                     const float* __restrict__ fc2_w,
                                                     const float* __restrict__ fc2_b,
                                                     const float* __restrict__ fc3_w,
                                                     const float* __restrict__ fc3_b,
                                                     float* __restrict__ out) {
    __shared__ float red[252];
    __shared__ float z1[84];
    __shared__ float z2[24];
    const int t = threadIdx.x;
    if (t < 252) {
        const int j = t % 84;
        const int sl = t / 84;
        const int b0 = sl * 66;
        const int b1 = (b0 + 66 < 196) ? (b0 + 66) : 196;
        float s = 0.f;
        for (int b = b0; b < b1; b += 2)
            s += partial[(size_t)b * 88 + j] + partial[(size_t)(b + 1) * 88 + j];
        red[t] = s;
    }
    __syncthreads();
    if (t < 84) z1[t] = elu1(red[t] + red[t + 84] + red[t + 168] + fc1_b[t]);
    __syncthreads();
    if (t < 24) {
        float a = fc2_b[t];
        for (int i = 0; i < 84; ++i) a = fmaf(z1[i], fc2_w[i * 24 + t], a);
        z2[t] = elu1(a);
    }
    __syncthreads();
    if (t == 0) {
        float z3[2];
        #pragma unroll
        for (int jj = 0; jj < 2; ++jj) {
            float a = fc3_b[jj];
            for (int i = 0; i < 24; ++i) a = fmaf(z2[i], fc3_w[i * 2 + jj], a);
            z3[jj] = a;
        }
        float m = fmaxf(z3[0], z3[1]);
        float l = m + logf(__expf(z3[0] - m) + __expf(z3[1] - m));
        out[0] = z3[0] - l;
        out[1] = z3[1] - l;
    }
}

extern "C" void kernel_launch(void* const* d_in, const int* in_sizes, int n_in,
                              void* d_out, int out_size, void* d_ws, size_t ws_size,
                              hipStream_t stream) {
    const float* x        = (const float*)d_in[0];
    const int*   ei       = (const int*)d_in[1];
    const float* W1       = (const float*)d_in[2];
    const float* att_src1 = (const float*)d_in[3];
    const float* att_dst1 = (const float*)d_in[4];
    const float* b1       = (const float*)d_in[5];
    const float* W2       = (const float*)d_in[6];
    const float* att_src2 = (const float*)d_in[7];
    const float* att_dst2 = (const float*)d_in[8];
    const float* b2       = (const float*)d_in[9];
    const float* fc1_w    = (const float*)d_in[10];
    const float* fc1_b    = (const float*)d_in[11];
    const float* fc2_w    = (const float*)d_in[12];
    const float* fc2_b    = (const float*)d_in[13];
    const float* fc3_w    = (const float*)d_in[14];
    const float* fc3_b    = (const float*)d_in[15];
    float* out = (float*)d_out;

    char* ws = (char*)d_ws;
    unsigned int* h1b = (unsigned int*)(ws + 0);         // 12,800,000 B
    float* hbuf   = (float*)(ws + 12800000);             // 25,600,000 B
    float* a_src1 = (float*)(ws + 38400000);             // 1,600,000 B
    float* a_dst1 = (float*)(ws + 40000000);             // 1,600,000 B
    float* h2     = (float*)(ws + 41600000);             // 1,600,000 B
    float* a_src2 = (float*)(ws + 43200000);             // 200,000 B
    float* a_dst2 = (float*)(ws + 43400000);             // 200,000 B
    int*   counts = (int*)  (ws + 43600000);             // 200,000 B
    int*   rowptr = (int*)  (ws + 43800000);             // 200,064 B
    int*   cursor = (int*)  (ws + 44000064);             // 200,000 B
    int*   esrc   = (int*)  (ws + 44200064);             // 3,400,000 B
    float* partial= (float*)(ws + 47600064);             // 196*88*4 = 68,992 B
    uint4* wbf    = (uint4*)(ws + 47669056);             // 32,768 B

    wprep_kernel<<<8, 256, 0, stream>>>(W1, wbf);
    init_counts_kernel<<<(N_NODES + 255) / 256, 256, 0, stream>>>(counts);
    hist_kernel<<<(NE + 255) / 256, 256, 0, stream>>>(ei, counts);
    scan_kernel<<<1, 1024, 0, stream>>>(counts, rowptr, cursor);
    fill_kernel<<<(NE + N_NODES + 255) / 256, 256, 0, stream>>>(ei, cursor, esrc);

    gemm1_kernel<<<(N_NODES + 63) / 64, 256, 0, stream>>>(x, wbf, att_src1, att_dst1, h1b, a_src1, a_dst1);
    agg1_kernel<<<(N_NODES + 3) / 4, 256, 0, stream>>>(h1b, a_src1, a_dst1, rowptr, esrc, b1, hbuf);

    gemm2_kernel<<<(N_NODES + 31) / 32, 256, 0, stream>>>(hbuf, W2, att_src2, att_dst2, h2, a_src2, a_dst2);
    agg2fc1_kernel<<<(N_NODES + 255) / 256, 256, 0, stream>>>(h2, a_src2, a_dst2, rowptr, esrc, b2, fc1_w, partial);
    fctail_kernel<<<1, 256, 0, stream>>>(partial, fc1_b, fc2_w, fc2_b, fc3_w, fc3_b, out);
}

// Round 6
// 256.487 us; speedup vs baseline: 1.6263x; 1.0681x over previous
//
#include <hip/hip_runtime.h>
#include <math.h>

#define N_NODES 50000
#define F_IN 128
#define NE 800000
#define NH1 8
#define ND1 16
#define ND2 8
#define NEG 0.2f
#define ZLEN (N_NODES * ND2)      // 400000
#define NBLK 196                  // ceil(50000/256)
#define FC1_RPB 240
#define FC1_NB 1667               // ceil(400000/240)

typedef __attribute__((ext_vector_type(8))) short bf16x8;   // 8 bf16 (4 VGPRs)
typedef __attribute__((ext_vector_type(4))) float f32x4;

__device__ __forceinline__ float lrelu(float v) { return v > 0.f ? v : NEG * v; }
__device__ __forceinline__ float elu1(float v)  { return v > 0.f ? v : (__expf(v) - 1.f); }

__device__ __forceinline__ unsigned short f2bf(float f) {
    union { float f; unsigned int i; } c; c.f = f;
    unsigned int u = c.i;
    return (unsigned short)((u + 0x7FFFu + ((u >> 16) & 1u)) >> 16);
}
__device__ __forceinline__ float bflo(unsigned int u) {
    union { unsigned int i; float f; } c; c.i = u << 16; return c.f;
}
__device__ __forceinline__ float bfhi(unsigned int u) {
    union { unsigned int i; float f; } c; c.i = u & 0xFFFF0000u; return c.f;
}
// int64-vs-int32 edge dtype: high words of first 4 entries all zero => int64
__device__ __forceinline__ int ei_is64(const int* __restrict__ ei) {
    return ((ei[1] | ei[3] | ei[5] | ei[7]) == 0) ? 1 : 0;
}

// ---------------- prep: W1 -> bf16 swizzled + counts init (fused) ----------------
__global__ __launch_bounds__(256) void prep_kernel(const float* __restrict__ W,
                                                   uint4* __restrict__ wbf,
                                                   int* __restrict__ counts) {
    int i = blockIdx.x * 256 + threadIdx.x;
    if (i < N_NODES) counts[i] = 1;   // self-loop
    if (i < 2048) {
        int col = i >> 4, kc = i & 15;
        unsigned int u[4];
        #pragma unroll
        for (int jj = 0; jj < 4; ++jj) {
            unsigned int lo = f2bf(W[(kc * 8 + 2 * jj) * 128 + col]);
            unsigned int hi = f2bf(W[(kc * 8 + 2 * jj + 1) * 128 + col]);
            u[jj] = lo | (hi << 16);
        }
        uint4 v; v.x = u[0]; v.y = u[1]; v.z = u[2]; v.w = u[3];
        wbf[col * 16 + (kc ^ (col & 15))] = v;
    }
}

// ---------------- CSR build ----------------
__global__ void hist_kernel(const int* __restrict__ ei, int* __restrict__ counts) {
    int e = blockIdx.x * blockDim.x + threadIdx.x;
    if (e >= NE) return;
    int is64 = ei_is64(ei);
    int d = is64 ? ei[2 * NE + 2 * e] : ei[NE + e];
    atomicAdd(&counts[d], 1);
}

// parallel scan, 3 stages
__global__ __launch_bounds__(256) void scan1_kernel(const int* __restrict__ counts,
                                                    int* __restrict__ bsum) {
    const int t = threadIdx.x;
    int i = blockIdx.x * 256 + t;
    int v = (i < N_NODES) ? counts[i] : 0;
    #pragma unroll
    for (int off = 32; off; off >>= 1) v += __shfl_down(v, off, 64);
    __shared__ int ws[4];
    if ((t & 63) == 0) ws[t >> 6] = v;
    __syncthreads();
    if (t == 0) bsum[blockIdx.x] = ws[0] + ws[1] + ws[2] + ws[3];
}

__global__ __launch_bounds__(256) void scan2_kernel(const int* __restrict__ bsum,
                                                    int* __restrict__ boff) {
    const int t = threadIdx.x;
    const int lane = t & 63, w = t >> 6;
    int v = (t < NBLK) ? bsum[t] : 0;
    int incl = v;
    #pragma unroll
    for (int off = 1; off < 64; off <<= 1) {
        int u = __shfl_up(incl, off, 64);
        if (lane >= off) incl += u;
    }
    __shared__ int wsum[4];
    __shared__ int wpre[4];
    if (lane == 63) wsum[w] = incl;
    __syncthreads();
    if (t == 0) { int s = 0; for (int j = 0; j < 4; ++j) { wpre[j] = s; s += wsum[j]; } }
    __syncthreads();
    if (t < NBLK) boff[t] = incl - v + wpre[w];   // exclusive prefix
}

__global__ __launch_bounds__(256) void scan3_kernel(const int* __restrict__ counts,
                                                    const int* __restrict__ boff,
                                                    int* __restrict__ rowptr,
                                                    int* __restrict__ cursor) {
    const int t = threadIdx.x;
    const int lane = t & 63, w = t >> 6;
    int i = blockIdx.x * 256 + t;
    int v = (i < N_NODES) ? counts[i] : 0;
    int incl = v;
    #pragma unroll
    for (int off = 1; off < 64; off <<= 1) {
        int u = __shfl_up(incl, off, 64);
        if (lane >= off) incl += u;
    }
    __shared__ int wsum[4];
    __shared__ int wpre[4];
    if (lane == 63) wsum[w] = incl;
    __syncthreads();
    if (t == 0) { int s = 0; for (int j = 0; j < 4; ++j) { wpre[j] = s; s += wsum[j]; } }
    __syncthreads();
    incl += wpre[w] + boff[blockIdx.x];
    if (i < N_NODES) { rowptr[i + 1] = incl; cursor[i] = incl - v; }
    if (i == 0) rowptr[0] = 0;
}

__global__ void fill_kernel(const int* __restrict__ ei,
                            int* __restrict__ cursor, int* __restrict__ esrc) {
    int i = blockIdx.x * blockDim.x + threadIdx.x;
    if (i >= NE + N_NODES) return;
    int s, d;
    if (i < NE) {
        int is64 = ei_is64(ei);
        if (is64) { s = ei[2 * i]; d = ei[2 * NE + 2 * i]; }
        else      { s = ei[i];     d = ei[NE + i]; }
    } else {
        s = d = i - NE;
    }
    int slot = atomicAdd(&cursor[d], 1);
    esrc[slot] = s;
}

// ---------------- conv1 GEMM via MFMA: h1 = x @ W1, fused att scores, bf16 packed out ----
__global__ __launch_bounds__(256) void gemm1_kernel(const float* __restrict__ x,
                                                    const uint4* __restrict__ wbf,
                                                    const float* __restrict__ att_src,
                                                    const float* __restrict__ att_dst,
                                                    unsigned int* __restrict__ h1b,
                                                    float* __restrict__ a_src1,
                                                    float* __restrict__ a_dst1) {
    __shared__ uint4 Xs[1024];   // 64 rows x 16 chunks (swizzled), 16 KB
    __shared__ uint4 Ws[2048];   // 128 cols x 16 chunks (pre-swizzled), 32 KB
    const int t = threadIdx.x;
    const int row0 = blockIdx.x * 64;

    #pragma unroll
    for (int p = 0; p < 8; ++p) Ws[p * 256 + t] = wbf[p * 256 + t];

    #pragma unroll
    for (int p = 0; p < 4; ++p) {
        int cidx = p * 256 + t;
        int row = cidx >> 4, c = cidx & 15;
        int grow = row0 + row;
        float4 xa = make_float4(0.f, 0.f, 0.f, 0.f);
        float4 xb = make_float4(0.f, 0.f, 0.f, 0.f);
        if (grow < N_NODES) {
            xa = *reinterpret_cast<const float4*>(x + (size_t)grow * F_IN + c * 8);
            xb = *reinterpret_cast<const float4*>(x + (size_t)grow * F_IN + c * 8 + 4);
        }
        uint4 u;
        u.x = (unsigned int)f2bf(xa.x) | ((unsigned int)f2bf(xa.y) << 16);
        u.y = (unsigned int)f2bf(xa.z) | ((unsigned int)f2bf(xa.w) << 16);
        u.z = (unsigned int)f2bf(xb.x) | ((unsigned int)f2bf(xb.y) << 16);
        u.w = (unsigned int)f2bf(xb.z) | ((unsigned int)f2bf(xb.w) << 16);
        Xs[row * 16 + (c ^ (row & 15))] = u;
    }
    __syncthreads();

    const int wv = t >> 6;
    const int l  = t & 63;
    const int d  = l & 15;
    const int g  = l >> 4;
    const int arow = wv * 16 + d;

    f32x4 acc[8];
    #pragma unroll
    for (int n = 0; n < 8; ++n) { acc[n][0] = 0.f; acc[n][1] = 0.f; acc[n][2] = 0.f; acc[n][3] = 0.f; }

    #pragma unroll
    for (int ks = 0; ks < 4; ++ks) {
        int kc = ks * 4 + g;
        union { uint4 u; bf16x8 v; } A;
        A.u = Xs[arow * 16 + (kc ^ d)];
        #pragma unroll
        for (int n = 0; n < 8; ++n) {
            union { uint4 u; bf16x8 v; } B;
            B.u = Ws[(n * 16 + d) * 16 + (kc ^ d)];
            acc[n] = __builtin_amdgcn_mfma_f32_16x16x32_bf16(A.v, B.v, acc[n], 0, 0, 0);
        }
    }

    float as8[8], ad8[8];
    #pragma unroll
    for (int n = 0; n < 8; ++n) { as8[n] = att_src[n * 16 + d]; ad8[n] = att_dst[n * 16 + d]; }
    #pragma unroll
    for (int n = 0; n < 8; ++n) {
        #pragma unroll
        for (int r = 0; r < 4; ++r) {
            float ps = acc[n][r] * as8[n];
            float pd = acc[n][r] * ad8[n];
            #pragma unroll
            for (int off = 1; off < 16; off <<= 1) {
                ps += __shfl_xor(ps, off, 16);
                pd += __shfl_xor(pd, off, 16);
            }
            int grow = row0 + wv * 16 + g * 4 + r;
            if (d == 0 && grow < N_NODES) {
                a_src1[grow * 8 + n] = ps;
                a_dst1[grow * 8 + n] = pd;
            }
        }
    }
    #pragma unroll
    for (int n = 0; n < 8; ++n) {
        #pragma unroll
        for (int r = 0; r < 4; ++r) {
            float lo = acc[n][r];
            float hi = __shfl_xor(lo, 1, 64);
            int grow = row0 + wv * 16 + g * 4 + r;
            if (((d & 1) == 0) && grow < N_NODES) {
                unsigned int u = (unsigned int)f2bf(lo) | ((unsigned int)f2bf(hi) << 16);
                h1b[(size_t)grow * 64 + n * 8 + (d >> 1)] = u;
            }
        }
    }
}

// ---------------- conv1 aggregation: one wave per dst node, bf16 gather, 8-deep ----------
__global__ __launch_bounds__(256) void agg1_kernel(const unsigned int* __restrict__ h1b,
                                                   const float* __restrict__ a_src,
                                                   const float* __restrict__ a_dst,
                                                   const int* __restrict__ rowptr,
                                                   const int* __restrict__ esrc,
                                                   const float* __restrict__ b1,
                                                   float* __restrict__ hout) {
    int wid = (blockIdx.x * 256 + threadIdx.x) >> 6;   // node id (wave-uniform)
    if (wid >= N_NODES) return;
    const int lane = threadIdx.x & 63;
    const int h = lane >> 3;
    const float ad = a_dst[wid * 8 + h];
    float acc0 = 0.f, acc1 = 0.f, den = 0.f;
    int j = rowptr[wid];
    const int jend = rowptr[wid + 1];
    for (; j + 8 <= jend; j += 8) {
        int s[8];
        #pragma unroll
        for (int k = 0; k < 8; ++k) s[k] = esrc[j + k];
        unsigned int u[8];
        #pragma unroll
        for (int k = 0; k < 8; ++k) u[k] = h1b[(size_t)s[k] * 64 + lane];
        float e[8];
        #pragma unroll
        for (int k = 0; k < 8; ++k) e[k] = a_src[s[k] * 8 + h];
        #pragma unroll
        for (int k = 0; k < 8; ++k) {
            float p = __expf(lrelu(e[k] + ad));
            den += p;
            acc0 = fmaf(p, bflo(u[k]), acc0);
            acc1 = fmaf(p, bfhi(u[k]), acc1);
        }
    }
    for (; j + 4 <= jend; j += 4) {
        int s0 = esrc[j], s1 = esrc[j + 1], s2 = esrc[j + 2], s3 = esrc[j + 3];
        unsigned int u0 = h1b[(size_t)s0 * 64 + lane];
        unsigned int u1 = h1b[(size_t)s1 * 64 + lane];
        unsigned int u2 = h1b[(size_t)s2 * 64 + lane];
        unsigned int u3 = h1b[(size_t)s3 * 64 + lane];
        float e0 = a_src[s0 * 8 + h], e1 = a_src[s1 * 8 + h];
        float e2 = a_src[s2 * 8 + h], e3 = a_src[s3 * 8 + h];
        float p0 = __expf(lrelu(e0 + ad));
        float p1 = __expf(lrelu(e1 + ad));
        float p2 = __expf(lrelu(e2 + ad));
        float p3 = __expf(lrelu(e3 + ad));
        den += (p0 + p1) + (p2 + p3);
        acc0 = fmaf(p0, bflo(u0), acc0); acc1 = fmaf(p0, bfhi(u0), acc1);
        acc0 = fmaf(p1, bflo(u1), acc0); acc1 = fmaf(p1, bfhi(u1), acc1);
        acc0 = fmaf(p2, bflo(u2), acc0); acc1 = fmaf(p2, bfhi(u2), acc1);
        acc0 = fmaf(p3, bflo(u3), acc0); acc1 = fmaf(p3, bfhi(u3), acc1);
    }
    for (; j < jend; ++j) {
        int s = esrc[j];
        unsigned int u = h1b[(size_t)s * 64 + lane];
        float e = a_src[s * 8 + h];
        float p = __expf(lrelu(e + ad));
        den += p;
        acc0 = fmaf(p, bflo(u), acc0);
        acc1 = fmaf(p, bfhi(u), acc1);
    }
    float inv = 1.f / den;
    float2 bb = *reinterpret_cast<const float2*>(b1 + 2 * lane);
    float o0 = elu1(acc0 * inv + bb.x);
    float o1 = elu1(acc1 * inv + bb.y);
    *reinterpret_cast<float2*>(hout + (size_t)wid * F_IN + 2 * lane) = make_float2(o0, o1);
}

// ---------------- conv2 GEMM + attention scores ----------------
__global__ __launch_bounds__(256) void gemm2_kernel(const float* __restrict__ h,
                                                    const float* __restrict__ W2,
                                                    const float* __restrict__ att_src2,
                                                    const float* __restrict__ att_dst2,
                                                    float* __restrict__ h2,
                                                    float* __restrict__ a_src2,
                                                    float* __restrict__ a_dst2) {
    __shared__ float Ws[F_IN * ND2];     // 4 KB
    __shared__ float Hs[32 * 132];       // padded, ~16.9 KB
    int t = threadIdx.x;
    int node0 = blockIdx.x * 32;
    #pragma unroll
    for (int i = 0; i < 4; ++i) { int idx = i * 256 + t; Ws[idx] = W2[idx]; }
    #pragma unroll
    for (int i = 0; i < 4; ++i) {
        int fidx = i * 256 + t;
        int r = fidx >> 5;
        int c4 = fidx & 31;
        int grow = node0 + r;
        float4 v = make_float4(0.f, 0.f, 0.f, 0.f);
        if (grow < N_NODES) v = *reinterpret_cast<const float4*>(h + (size_t)grow * F_IN + c4 * 4);
        *reinterpret_cast<float4*>(&Hs[r * 132 + c4 * 4]) = v;
    }
    __syncthreads();
    int nsub = t >> 3, d = t & 7;
    int node = node0 + nsub;
    float acc = 0.f;
    #pragma unroll 8
    for (int k = 0; k < F_IN; ++k)
        acc = fmaf(Hs[nsub * 132 + k], Ws[k * ND2 + d], acc);
    float vs = acc * att_src2[d];
    float vd = acc * att_dst2[d];
    #pragma unroll
    for (int off = 4; off >= 1; off >>= 1) {
        vs += __shfl_xor(vs, off, 8);
        vd += __shfl_xor(vd, off, 8);
    }
    if (node < N_NODES) {
        h2[node * ND2 + d] = acc;
        if (d == 0) { a_src2[node] = vs; a_dst2[node] = vd; }
    }
}

// ---------------- conv2 aggregation: one thread per node ----------------
__global__ void agg2_kernel(const float* __restrict__ h2,
                            const float* __restrict__ a_src2, const float* __restrict__ a_dst2,
                            const int* __restrict__ rowptr, const int* __restrict__ esrc,
                            const float* __restrict__ b2, float* __restrict__ g) {
    int n = blockIdx.x * blockDim.x + threadIdx.x;
    if (n >= N_NODES) return;
    float ad = a_dst2[n];
    float acc[8] = {0.f, 0.f, 0.f, 0.f, 0.f, 0.f, 0.f, 0.f};
    float den = 0.f;
    int jend = rowptr[n + 1];
    for (int j = rowptr[n]; j < jend; ++j) {
        int s = esrc[j];
        float p = __expf(lrelu(a_src2[s] + ad));
        den += p;
        float4 va = *reinterpret_cast<const float4*>(h2 + s * ND2);
        float4 vb = *reinterpret_cast<const float4*>(h2 + s * ND2 + 4);
        acc[0] = fmaf(p, va.x, acc[0]); acc[1] = fmaf(p, va.y, acc[1]);
        acc[2] = fmaf(p, va.z, acc[2]); acc[3] = fmaf(p, va.w, acc[3]);
        acc[4] = fmaf(p, vb.x, acc[4]); acc[5] = fmaf(p, vb.y, acc[5]);
        acc[6] = fmaf(p, vb.z, acc[6]); acc[7] = fmaf(p, vb.w, acc[7]);
    }
    float inv = 1.f / den;
    float4 o0 = make_float4(elu1(acc[0] * inv + b2[0]), elu1(acc[1] * inv + b2[1]),
                            elu1(acc[2] * inv + b2[2]), elu1(acc[3] * inv + b2[3]));
    float4 o1 = make_float4(elu1(acc[4] * inv + b2[4]), elu1(acc[5] * inv + b2[5]),
                            elu1(acc[6] * inv + b2[6]), elu1(acc[7] * inv + b2[7]));
    *reinterpret_cast<float4*>(g + n * ND2)     = o0;
    *reinterpret_cast<float4*>(g + n * ND2 + 4) = o1;
}

// ---------------- fc1 stage 1: 1667 blocks x 240 rows, 4-deep float4, no atomics -------
__global__ __launch_bounds__(256) void fc1_stage1(const float* __restrict__ z,
                                                  const float* __restrict__ w,
                                                  float* __restrict__ partial) {
    __shared__ float zs[FC1_RPB];
    __shared__ float4 red[252];
    const int t = threadIdx.x;
    const int b = blockIdx.x;
    const int r0 = b * FC1_RPB;
    if (t < FC1_RPB) {
        int gr = r0 + t;
        zs[t] = (gr < ZLEN) ? z[gr] : 0.f;
    }
    __syncthreads();
    const int c4 = t % 21;
    const int rr = t / 21;
    if (t < 252) {
        float4 a = make_float4(0.f, 0.f, 0.f, 0.f);
        const float4* __restrict__ w4 = reinterpret_cast<const float4*>(w);
        if (r0 + FC1_RPB <= ZLEN) {
            #pragma unroll
            for (int bq = 0; bq < 5; ++bq) {
                float4 wv[4];
                float  zv[4];
                #pragma unroll
                for (int u = 0; u < 4; ++u) {
                    int i = bq * 48 + u * 12 + rr;
                    wv[u] = w4[(size_t)(r0 + i) * 21 + c4];
                    zv[u] = zs[i];
                }
                #pragma unroll
                for (int u = 0; u < 4; ++u) {
                    a.x = fmaf(zv[u], wv[u].x, a.x);
                    a.y = fmaf(zv[u], wv[u].y, a.y);
                    a.z = fmaf(zv[u], wv[u].z, a.z);
                    a.w = fmaf(zv[u], wv[u].w, a.w);
                }
            }
        } else {
            for (int i = rr; i < FC1_RPB; i += 12) {
                if (r0 + i < ZLEN) {
                    float4 wv = w4[(size_t)(r0 + i) * 21 + c4];
                    float  zv = zs[i];
                    a.x = fmaf(zv, wv.x, a.x); a.y = fmaf(zv, wv.y, a.y);
                    a.z = fmaf(zv, wv.z, a.z); a.w = fmaf(zv, wv.w, a.w);
                }
            }
        }
        red[t] = a;
    }
    __syncthreads();
    if (t < 21) {
        float4 s = red[t];
        #pragma unroll
        for (int k = 1; k < 12; ++k) {
            float4 v = red[k * 21 + t];
            s.x += v.x; s.y += v.y; s.z += v.z; s.w += v.w;
        }
        *reinterpret_cast<float4*>(partial + (size_t)b * 88 + t * 4) = s;
    }
}

// ---------------- tail: reduce 1667 partials + MLP + log_softmax ----------------
__global__ __launch_bounds__(1024) void fctail_kernel(const float* __restrict__ partial,
                                                      const float* __restrict__ fc1_b,
                                                      const float* __restrict__ fc2_w,
                                                      const float* __restrict__ fc2_b,
                                                      const float* __restrict__ fc3_w,
                                                      const float* __restrict__ fc3_b,
                                                      float* __restrict__ out) {
    __shared__ float red[1008];
    __shared__ float z1[84];
    __shared__ float z2[24];
    const int t = threadIdx.x;
    if (t < 1008) {
        const int j  = t % 84;
        const int sl = t / 84;          // 0..11
        float s = 0.f;
        for (int b = sl; b < FC1_NB; b += 12)
            s += partial[(size_t)b * 88 + j];
        red[t] = s;
    }
    __syncthreads();
    if (t < 84) {
        float s = 0.f;
        #pragma unroll
        for (int sl = 0; sl < 12; ++sl) s += red[sl * 84 + t];
        z1[t] = elu1(s + fc1_b[t]);
    }
    __syncthreads();
    if (t < 24) {
        float a = fc2_b[t];
        for (int i = 0; i < 84; ++i) a = fmaf(z1[i], fc2_w[i * 24 + t], a);
        z2[t] = elu1(a);
    }
    __syncthreads();
    if (t == 0) {
        float z3[2];
        #pragma unroll
        for (int jj = 0; jj < 2; ++jj) {
            float a = fc3_b[jj];
            for (int i = 0; i < 24; ++i) a = fmaf(z2[i], fc3_w[i * 2 + jj], a);
            z3[jj] = a;
        }
        float m = fmaxf(z3[0], z3[1]);
        float l = m + logf(__expf(z3[0] - m) + __expf(z3[1] - m));
        out[0] = z3[0] - l;
        out[1] = z3[1] - l;
    }
}

extern "C" void kernel_launch(void* const* d_in, const int* in_sizes, int n_in,
                              void* d_out, int out_size, void* d_ws, size_t ws_size,
                              hipStream_t stream) {
    const float* x        = (const float*)d_in[0];
    const int*   ei       = (const int*)d_in[1];
    const float* W1       = (const float*)d_in[2];
    const float* att_src1 = (const float*)d_in[3];
    const float* att_dst1 = (const float*)d_in[4];
    const float* b1       = (const float*)d_in[5];
    const float* W2       = (const float*)d_in[6];
    const float* att_src2 = (const float*)d_in[7];
    const float* att_dst2 = (const float*)d_in[8];
    const float* b2       = (const float*)d_in[9];
    const float* fc1_w    = (const float*)d_in[10];
    const float* fc1_b    = (const float*)d_in[11];
    const float* fc2_w    = (const float*)d_in[12];
    const float* fc2_b    = (const float*)d_in[13];
    const float* fc3_w    = (const float*)d_in[14];
    const float* fc3_b    = (const float*)d_in[15];
    float* out = (float*)d_out;

    char* ws = (char*)d_ws;
    unsigned int* h1b = (unsigned int*)(ws + 0);         // 12,800,000 B
    float* hbuf   = (float*)(ws + 12800000);             // 25,600,000 B
    float* a_src1 = (float*)(ws + 38400000);             // 1,600,000 B
    float* a_dst1 = (float*)(ws + 40000000);             // 1,600,000 B
    float* h2     = (float*)(ws + 41600000);             // 1,600,000 B
    float* a_src2 = (float*)(ws + 43200000);             // 200,000 B
    float* a_dst2 = (float*)(ws + 43400000);             // 200,000 B
    float* g      = (float*)(ws + 43600000);             // 1,600,000 B
    int*   counts = (int*)  (ws + 45200000);             // 200,000 B
    int*   rowptr = (int*)  (ws + 45400000);             // 200,064 B
    int*   cursor = (int*)  (ws + 45600064);             // 200,000 B
    int*   esrc   = (int*)  (ws + 45800064);             // 3,400,000 B
    float* partial= (float*)(ws + 49200064);             // 1667*88*4 = 586,784 B
    uint4* wbf    = (uint4*)(ws + 49786848);             // 32,768 B
    int*   bsum   = (int*)  (ws + 49819616);             // 784 B
    int*   boff   = (int*)  (ws + 49820400);             // 784 B

    prep_kernel<<<NBLK, 256, 0, stream>>>(W1, wbf, counts);
    hist_kernel<<<(NE + 255) / 256, 256, 0, stream>>>(ei, counts);
    scan1_kernel<<<NBLK, 256, 0, stream>>>(counts, bsum);
    scan2_kernel<<<1, 256, 0, stream>>>(bsum, boff);
    scan3_kernel<<<NBLK, 256, 0, stream>>>(counts, boff, rowptr, cursor);
    fill_kernel<<<(NE + N_NODES + 255) / 256, 256, 0, stream>>>(ei, cursor, esrc);

    gemm1_kernel<<<(N_NODES + 63) / 64, 256, 0, stream>>>(x, wbf, att_src1, att_dst1, h1b, a_src1, a_dst1);
    agg1_kernel<<<(N_NODES + 3) / 4, 256, 0, stream>>>(h1b, a_src1, a_dst1, rowptr, esrc, b1, hbuf);

    gemm2_kernel<<<(N_NODES + 31) / 32, 256, 0, stream>>>(hbuf, W2, att_src2, att_dst2, h2, a_src2, a_dst2);
    agg2_kernel<<<(N_NODES + 255) / 256, 256, 0, stream>>>(h2, a_src2, a_dst2, rowptr, esrc, b2, g);

    fc1_stage1<<<FC1_NB, 256, 0, stream>>>(g, fc1_w, partial);
    fctail_kernel<<<1, 1024, 0, stream>>>(partial, fc1_b, fc2_w, fc2_b, fc3_w, fc3_b, out);
}